// Round 1
// baseline (145.751 us; speedup 1.0000x reference)
//
#include <hip/hip_runtime.h>
#include <hip/hip_bf16.h>

// Problem dims
#define BB 4
#define SS 1024
#define EE 192
#define HH 64
// D = 3 (head dim)

constexpr int BH = BB * HH;  // 256

// ws layout (in floats)
constexpr size_t OFF_WQR = 0;                         // E*E rotated+scaled Wq
constexpr size_t OFF_WKR = OFF_WQR + (size_t)EE*EE;   // E*E rotated Wk
constexpr size_t OFF_Q   = OFF_WKR + (size_t)EE*EE;   // (B*H, S, 4) padded
constexpr size_t SZ_Q    = (size_t)BH*SS*4;
constexpr size_t OFF_KV  = OFF_Q + SZ_Q;              // (B*H, S, 8): k0 k1 k2 _ v0 v1 v2 _
constexpr size_t SZ_KV   = (size_t)BH*SS*8;
constexpr size_t OFF_AO  = OFF_KV + SZ_KV;            // (B, S, E) attention output

static __device__ __forceinline__ float fast_exp2(float x) {
#if __has_builtin(__builtin_amdgcn_exp2f)
  return __builtin_amdgcn_exp2f(x);
#else
  return exp2f(x);
#endif
}
static __device__ __forceinline__ float fast_rcp(float x) {
#if __has_builtin(__builtin_amdgcn_rcpf)
  return __builtin_amdgcn_rcpf(x);
#else
  return 1.0f / x;
#endif
}

// Fold per-head 3x3 rotation into Wq and Wk (fp32, exact restructuring).
// WqR additionally carries log2(e)/sqrt(3) so attention exp is a single v_exp_f32.
__global__ __launch_bounds__(256) void fold_rot_k(
    const float* __restrict__ Wq, const float* __restrict__ Wk,
    const float* __restrict__ rot, float* __restrict__ WqR, float* __restrict__ WkR)
{
  int t = blockIdx.x * 256 + threadIdx.x;
  if (t >= 2 * EE * EE) return;
  int mat = t / (EE * EE);
  int idx = t % (EE * EE);
  int op = idx / EE, e = idx % EE;      // op = h*3 + e'
  int h = op / 3, ep = op - h * 3;
  const float* W = mat ? Wk : Wq;
  float acc = 0.f;
#pragma unroll
  for (int d = 0; d < 3; ++d)
    acc += rot[h * 9 + d * 3 + ep] * W[(h * 3 + d) * EE + e];
  float scale = mat ? 1.0f : 0.8329876360019913f;  // log2(e)/sqrt(3)
  (mat ? WkR : WqR)[op * EE + e] = acc * scale;
}

// QKV projection GEMM: (4096 x 192) @ W^T for W in {WqR, WkR, Wv}.
// grid = (9 col-tiles, 64 row-tiles); tiles 0-2 -> Q, 3-5 -> K, 6-8 -> V.
// LDS tiles stored k-major (transposed) with pad 68 for aligned ds_read_b128.
__global__ __launch_bounds__(256) void gemm_qkv_k(
    const float* __restrict__ x, const float* __restrict__ WqR,
    const float* __restrict__ WkR, const float* __restrict__ Wv,
    float* __restrict__ Q, float* __restrict__ KV)
{
  __shared__ __align__(16) float xs[64][68];
  __shared__ __align__(16) float wsm[64][68];
  int bx = blockIdx.x;   // 0..8
  int by = blockIdx.y;   // 0..63
  int t = threadIdx.x;
  int sel = bx / 3;
  const float* W = (sel == 0) ? WqR : (sel == 1 ? WkR : Wv);
  int colBase = (bx % 3) * 64;
  int rowBase = by * 64;
  int lrow = t >> 2, lq = t & 3;
  int tr = t & 15, tc = t >> 4;
  float acc[4][4] = {};

  for (int kk = 0; kk < 3; ++kk) {
    const float* xg = x + (size_t)(rowBase + lrow) * EE + kk * 64;
    const float* wg = W + (size_t)(colBase + lrow) * EE + kk * 64;
    float4 xv[4], wv[4];
#pragma unroll
    for (int i = 0; i < 4; ++i) {
      xv[i] = ((const float4*)xg)[lq + 4 * i];
      wv[i] = ((const float4*)wg)[lq + 4 * i];
    }
    __syncthreads();
#pragma unroll
    for (int i = 0; i < 4; ++i) {
      int k0 = (lq + 4 * i) * 4;
      xs[k0 + 0][lrow] = xv[i].x; xs[k0 + 1][lrow] = xv[i].y;
      xs[k0 + 2][lrow] = xv[i].z; xs[k0 + 3][lrow] = xv[i].w;
      wsm[k0 + 0][lrow] = wv[i].x; wsm[k0 + 1][lrow] = wv[i].y;
      wsm[k0 + 2][lrow] = wv[i].z; wsm[k0 + 3][lrow] = wv[i].w;
    }
    __syncthreads();
#pragma unroll 8
    for (int k = 0; k < 64; ++k) {
      float4 a = *(const float4*)&xs[k][tr * 4];
      float4 bv = *(const float4*)&wsm[k][tc * 4];
      acc[0][0] += a.x * bv.x; acc[0][1] += a.x * bv.y; acc[0][2] += a.x * bv.z; acc[0][3] += a.x * bv.w;
      acc[1][0] += a.y * bv.x; acc[1][1] += a.y * bv.y; acc[1][2] += a.y * bv.z; acc[1][3] += a.y * bv.w;
      acc[2][0] += a.z * bv.x; acc[2][1] += a.z * bv.y; acc[2][2] += a.z * bv.z; acc[2][3] += a.z * bv.w;
      acc[3][0] += a.w * bv.x; acc[3][1] += a.w * bv.y; acc[3][2] += a.w * bv.z; acc[3][3] += a.w * bv.w;
    }
  }

#pragma unroll
  for (int i = 0; i < 4; ++i) {
    int r = rowBase + tr * 4 + i;
    int b = r >> 10, s = r & (SS - 1);
#pragma unroll
    for (int j = 0; j < 4; ++j) {
      int o = colBase + tc * 4 + j;
      int h = o / 3, d = o - h * 3;
      size_t base = ((size_t)(b * HH + h) * SS + s);
      if (sel == 0)      Q[base * 4 + d] = acc[i][j];
      else if (sel == 1) KV[base * 8 + d] = acc[i][j];
      else               KV[base * 8 + 4 + d] = acc[i][j];
    }
  }
}

// Attention: one block per (b,h). K/V (interleaved, 32KB) in LDS; each of 256
// threads owns 4 q-rows; online exp-sum accumulation, no max pass needed
// (scores bounded, fp32 range is ample). 1 exp per (row,key) pair.
__global__ __launch_bounds__(256) void attn_k(
    const float* __restrict__ Qw, const float* __restrict__ KVw, float* __restrict__ AO)
{
  __shared__ __align__(16) float kv[SS * 8];  // 32 KB
  int bh = blockIdx.x;
  int b = bh >> 6, h = bh & 63;
  const float* kvg = KVw + (size_t)bh * (SS * 8);
  for (int i = threadIdx.x; i < SS * 2; i += 256)
    ((float4*)kv)[i] = ((const float4*)kvg)[i];
  __syncthreads();

  const float* qg = Qw + (size_t)bh * (SS * 4);
  float q[4][3], l[4] = {0.f, 0.f, 0.f, 0.f}, o[4][3] = {};
  int r[4];
#pragma unroll
  for (int i = 0; i < 4; ++i) {
    r[i] = threadIdx.x + 256 * i;
    float4 qa = *(const float4*)&qg[r[i] * 4];
    q[i][0] = qa.x; q[i][1] = qa.y; q[i][2] = qa.z;
  }

#pragma unroll 2
  for (int j = 0; j < SS; ++j) {
    float4 kj = *(const float4*)&kv[j * 8];
    float4 vj = *(const float4*)&kv[j * 8 + 4];
#pragma unroll
    for (int i = 0; i < 4; ++i) {
      float s = q[i][0] * kj.x + q[i][1] * kj.y + q[i][2] * kj.z;
      float p = fast_exp2(s);   // exp(qk/sqrt(3)); log2e/sqrt3 folded into Q
      l[i] += p;
      o[i][0] += p * vj.x; o[i][1] += p * vj.y; o[i][2] += p * vj.z;
    }
  }

#pragma unroll
  for (int i = 0; i < 4; ++i) {
    float inv = fast_rcp(l[i]);
    float* dst = AO + ((size_t)(b * SS + r[i])) * EE + h * 3;
    dst[0] = o[i][0] * inv; dst[1] = o[i][1] * inv; dst[2] = o[i][2] * inv;
  }
}

// Output projection: AO (4096 x 192) @ Wo^T -> out. grid = (3, 64).
__global__ __launch_bounds__(256) void gemm_out_k(
    const float* __restrict__ x, const float* __restrict__ Wo, float* __restrict__ out)
{
  __shared__ __align__(16) float xs[64][68];
  __shared__ __align__(16) float wsm[64][68];
  int bx = blockIdx.x;   // 0..2
  int by = blockIdx.y;   // 0..63
  int t = threadIdx.x;
  int colBase = bx * 64;
  int rowBase = by * 64;
  int lrow = t >> 2, lq = t & 3;
  int tr = t & 15, tc = t >> 4;
  float acc[4][4] = {};

  for (int kk = 0; kk < 3; ++kk) {
    const float* xg = x + (size_t)(rowBase + lrow) * EE + kk * 64;
    const float* wg = Wo + (size_t)(colBase + lrow) * EE + kk * 64;
    float4 xv[4], wv[4];
#pragma unroll
    for (int i = 0; i < 4; ++i) {
      xv[i] = ((const float4*)xg)[lq + 4 * i];
      wv[i] = ((const float4*)wg)[lq + 4 * i];
    }
    __syncthreads();
#pragma unroll
    for (int i = 0; i < 4; ++i) {
      int k0 = (lq + 4 * i) * 4;
      xs[k0 + 0][lrow] = xv[i].x; xs[k0 + 1][lrow] = xv[i].y;
      xs[k0 + 2][lrow] = xv[i].z; xs[k0 + 3][lrow] = xv[i].w;
      wsm[k0 + 0][lrow] = wv[i].x; wsm[k0 + 1][lrow] = wv[i].y;
      wsm[k0 + 2][lrow] = wv[i].z; wsm[k0 + 3][lrow] = wv[i].w;
    }
    __syncthreads();
#pragma unroll 8
    for (int k = 0; k < 64; ++k) {
      float4 a = *(const float4*)&xs[k][tr * 4];
      float4 bv = *(const float4*)&wsm[k][tc * 4];
      acc[0][0] += a.x * bv.x; acc[0][1] += a.x * bv.y; acc[0][2] += a.x * bv.z; acc[0][3] += a.x * bv.w;
      acc[1][0] += a.y * bv.x; acc[1][1] += a.y * bv.y; acc[1][2] += a.y * bv.z; acc[1][3] += a.y * bv.w;
      acc[2][0] += a.z * bv.x; acc[2][1] += a.z * bv.y; acc[2][2] += a.z * bv.z; acc[2][3] += a.z * bv.w;
      acc[3][0] += a.w * bv.x; acc[3][1] += a.w * bv.y; acc[3][2] += a.w * bv.z; acc[3][3] += a.w * bv.w;
    }
  }

#pragma unroll
  for (int i = 0; i < 4; ++i) {
    int r = rowBase + tr * 4 + i;
#pragma unroll
    for (int j = 0; j < 4; ++j) {
      int o = colBase + tc * 4 + j;
      out[(size_t)r * EE + o] = acc[i][j];
    }
  }
}

extern "C" void kernel_launch(void* const* d_in, const int* in_sizes, int n_in,
                              void* d_out, int out_size, void* d_ws, size_t ws_size,
                              hipStream_t stream) {
  const float* x   = (const float*)d_in[0];
  const float* Wq  = (const float*)d_in[1];
  const float* Wk  = (const float*)d_in[2];
  const float* Wv  = (const float*)d_in[3];
  const float* Wo  = (const float*)d_in[4];
  const float* rot = (const float*)d_in[5];
  float* ws  = (float*)d_ws;
  float* WqR = ws + OFF_WQR;
  float* WkR = ws + OFF_WKR;
  float* Q   = ws + OFF_Q;
  float* KV  = ws + OFF_KV;
  float* AO  = ws + OFF_AO;
  float* out = (float*)d_out;

  fold_rot_k<<<dim3((2 * EE * EE + 255) / 256), 256, 0, stream>>>(Wq, Wk, rot, WqR, WkR);
  gemm_qkv_k<<<dim3(9, 64), 256, 0, stream>>>(x, WqR, WkR, Wv, Q, KV);
  attn_k<<<dim3(BH), 256, 0, stream>>>(Q, KV, AO);
  gemm_out_k<<<dim3(3, 64), 256, 0, stream>>>(AO, Wo, out);
}